// Round 10
// baseline (35.708 us; speedup 1.0000x reference)
//
#include <hip/hip_runtime.h>
#include <hip/hip_bf16.h>

#define LN_EPS 1e-5f
#define TSB 40                 // LDS tile row stride in bf16 (80B, 16B-aligned)
#define TILEB (32 * TSB)       // shorts per tile
#define MAGIC 0x5A5A7E1Du

typedef __attribute__((ext_vector_type(8))) short bf16x8;
typedef __attribute__((ext_vector_type(16))) float f32x16;

__device__ __forceinline__ short bf16b(float f) {
  return __builtin_bit_cast(short, __float2bfloat16(f));
}

__device__ __forceinline__ void wave_reduce2(float& s1, float& s2) {
  #pragma unroll
  for (int off = 32; off; off >>= 1) {
    s1 += __shfl_xor(s1, off);
    s2 += __shfl_xor(s2, off);
  }
}

// A-frag/B-frag read from a row-major-[32][TSB] LDS tile.
// Normal tile -> A-operand (lane m holds A[m][k]); transposed tile -> B-operand.
__device__ __forceinline__ bf16x8 frag_ld(const short* t, int l, int k0) {
  return *(const bf16x8*)&t[(l & 31) * TSB + ((l >> 5) << 3) + k0];
}

__device__ __forceinline__ int cd_row(int r, int l) {
  return (r & 3) + 8 * (r >> 2) + 4 * (l >> 5);   // verified C/D mapping
}

__device__ __forceinline__ void cd_store(short* t, int l, const f32x16 d,
                                         bool transp) {
  const int col = l & 31;
  if (transp) {
    #pragma unroll
    for (int r = 0; r < 16; ++r) t[col * TSB + cd_row(r, l)] = bf16b(d[r]);
  } else {
    #pragma unroll
    for (int r = 0; r < 16; ++r) t[cd_row(r, l) * TSB + col] = bf16b(d[r]);
  }
}

struct NodeParams {
  bf16x8 w0, w1;        // Ww^T B-fragments (k0=0,16)
  float wb;             // Wb[col]
  float ga[16], be[16]; // gamma/beta at this lane's 16 C/D positions
};

__device__ __forceinline__ NodeParams load_params(const float* __restrict__ Ww,
    const float* __restrict__ Wb, const float* __restrict__ gamma,
    const float* __restrict__ beta, int l) {
  NodeParams P;
  const int n = l & 31, kh = (l >> 5) * 8;
  float w[8];
  *(float4*)&w[0] = *(const float4*)&Ww[n * 32 + kh];
  *(float4*)&w[4] = *(const float4*)&Ww[n * 32 + kh + 4];
  #pragma unroll
  for (int i = 0; i < 8; ++i) P.w0[i] = bf16b(w[i]);
  *(float4*)&w[0] = *(const float4*)&Ww[n * 32 + kh + 16];
  *(float4*)&w[4] = *(const float4*)&Ww[n * 32 + kh + 20];
  #pragma unroll
  for (int i = 0; i < 8; ++i) P.w1[i] = bf16b(w[i]);
  P.wb = Wb[n];
  #pragma unroll
  for (int r = 0; r < 16; ++r) {
    const int idx = cd_row(r, l) * 32 + n;
    P.ga[r] = gamma[idx];
    P.be[r] = beta[idx];
  }
  return P;
}

__device__ __forceinline__ f32x16 mm32(const short* A, const short* B, int l) {
  f32x16 acc = {};
  acc = __builtin_amdgcn_mfma_f32_32x32x16_bf16(frag_ld(A, l, 0),
                                                frag_ld(B, l, 0), acc, 0, 0, 0);
  acc = __builtin_amdgcn_mfma_f32_32x32x16_bf16(frag_ld(A, l, 16),
                                                frag_ld(B, l, 16), acc, 0, 0, 0);
  return acc;
}

// fp32 global tile [32][32] -> LDS bf16, normal or transposed; one wave
__device__ __forceinline__ void stage_f32(short* dst,
                                          const float* __restrict__ src, int l,
                                          bool transp) {
  float v[16];
  #pragma unroll
  for (int q = 0; q < 4; ++q)
    *(float4*)&v[q * 4] = *(const float4*)&src[l * 16 + q * 4];
  const int row = l >> 1, c0 = (l & 1) * 16;
  if (transp) {
    #pragma unroll
    for (int i = 0; i < 16; ++i) dst[(c0 + i) * TSB + row] = bf16b(v[i]);
  } else {
    #pragma unroll
    for (int i = 0; i < 8; ++i) {
      unsigned lo = (unsigned short)bf16b(v[2 * i]);
      unsigned hi = (unsigned short)bf16b(v[2 * i + 1]);
      ((unsigned*)dst)[row * (TSB / 2) + (c0 >> 1) + i] = lo | (hi << 16);
    }
  }
}

// CW = C @ Ww^T precompute: stage C normal, 2 MFMA with register Ww^T frags,
// store transposed (B-operand layout) back into the same slot. Same-wave
// in-order LDS (proven cd_store->frag_ld pattern).
__device__ __forceinline__ void cw_prep(short* slot,
                                        const float* __restrict__ src,
                                        const NodeParams& P, int l) {
  stage_f32(slot, src, l, false);
  f32x16 cw = {};
  cw = __builtin_amdgcn_mfma_f32_32x32x16_bf16(frag_ld(slot, l, 0), P.w0, cw, 0, 0, 0);
  cw = __builtin_amdgcn_mfma_f32_32x32x16_bf16(frag_ld(slot, l, 16), P.w1, cw, 0, 0, 0);
  cd_store(slot, l, cw, true);
}

// Tree node, 2 dependent matmuls: X = (L@R)@CW + Wb; LN+ReLU.
// A = left child (normal), Bt = right child (transposed), CWt = C@Ww^T
// (transposed). T1 scratch overwrites A. Output -> dst (or fp32 fout).
__device__ __forceinline__ void node2(short* A, short* Bt, short* CWt,
                                      const NodeParams& P, int l, short* dst,
                                      bool transpOut, float* fout) {
  f32x16 t1 = mm32(A, Bt, l);
  cd_store(A, l, t1, false);            // T1 (normal, A-layout) into A slot
  f32x16 x = mm32(A, CWt, l);           // X = T1 @ CW
  float s1 = 0.f, s2 = 0.f;
  #pragma unroll
  for (int r = 0; r < 16; ++r) {
    x[r] += P.wb;
    s1 += x[r];
    s2 += x[r] * x[r];
  }
  wave_reduce2(s1, s2);
  const float mu = s1 * (1.f / 1024.f);
  const float rs = rsqrtf(s2 * (1.f / 1024.f) - mu * mu + LN_EPS);
  #pragma unroll
  for (int r = 0; r < 16; ++r)
    x[r] = fmaxf((x[r] - mu) * rs * P.ga[r] + P.be[r], 0.f);
  if (fout) {
    #pragma unroll
    for (int r = 0; r < 16; ++r) fout[cd_row(r, l) * 32 + (l & 31)] = x[r];
  } else {
    cd_store(dst, l, x, transpOut);
  }
}

// 16 bf16 values (lane l covers shorts 16l..16l+15) -> LDS tile, parity layout
__device__ __forceinline__ void lds_put16(short* dst, const short v[16], int l,
                                          bool transp) {
  const int row = l >> 1, c0 = (l & 1) * 16;
  if (transp) {
    #pragma unroll
    for (int i = 0; i < 16; ++i) dst[(c0 + i) * TSB + row] = v[i];
  } else {
    #pragma unroll
    for (int i = 0; i < 8; ++i) {
      unsigned lo = (unsigned short)v[2 * i];
      unsigned hi = (unsigned short)v[2 * i + 1];
      ((unsigned*)dst)[row * (TSB / 2) + (c0 >> 1) + i] = lo | (hi << 16);
    }
  }
}

// coherent (agent-scope) tile fetch: global compact bf16 -> LDS
__device__ __forceinline__ void fetch_tile(short* dstLds,
                                           const unsigned* __restrict__ src,
                                           int l, bool transp) {
  short v[16];
  #pragma unroll
  for (int i = 0; i < 8; ++i) {
    unsigned x = __hip_atomic_load(src + l * 8 + i, __ATOMIC_RELAXED,
                                   __HIP_MEMORY_SCOPE_AGENT);
    v[2 * i] = (short)(x & 0xFFFFu);
    v[2 * i + 1] = (short)(x >> 16);
  }
  lds_put16(dstLds, v, l, transp);
}

// coherent tile emit: LDS normal tile -> global compact bf16; 512 threads
__device__ __forceinline__ void emit512(unsigned* __restrict__ dst,
                                        const short* t, int u) {
  const int row = u >> 4, cp = u & 15;
  unsigned v = *(const unsigned*)&t[row * TSB + cp * 2];
  __hip_atomic_store(dst + u, v, __ATOMIC_RELAXED, __HIP_MEMORY_SCOPE_AGENT);
}

__device__ __forceinline__ void flag_set(unsigned* f) {
  __hip_atomic_store(f, MAGIC, __ATOMIC_RELAXED, __HIP_MEMORY_SCOPE_AGENT);
}

__device__ __forceinline__ void flag_wait(const unsigned* f) {
  while (__hip_atomic_load(f, __ATOMIC_RELAXED, __HIP_MEMORY_SCOPE_AGENT) !=
         MAGIC)
    __builtin_amdgcn_s_sleep(1);
  asm volatile("" ::: "memory");
}

// leaf: load fp32 tile, LN+ReLU in-wave, write bf16 with parity layout
__device__ __forceinline__ void leaf_ln(short* dst, const float* __restrict__ src,
                                        const float* __restrict__ gamma,
                                        const float* __restrict__ beta, int l,
                                        bool transp) {
  float v[16], ga[16], be[16];
  #pragma unroll
  for (int q = 0; q < 4; ++q) {
    *(float4*)&v[q * 4] = *(const float4*)&src[l * 16 + q * 4];
    *(float4*)&ga[q * 4] = *(const float4*)&gamma[l * 16 + q * 4];
    *(float4*)&be[q * 4] = *(const float4*)&beta[l * 16 + q * 4];
  }
  float s1 = 0.f, s2 = 0.f;
  #pragma unroll
  for (int i = 0; i < 16; ++i) { s1 += v[i]; s2 += v[i] * v[i]; }
  wave_reduce2(s1, s2);
  const float mu = s1 * (1.f / 1024.f);
  const float rs = rsqrtf(s2 * (1.f / 1024.f) - mu * mu + LN_EPS);
  short o[16];
  #pragma unroll
  for (int i = 0; i < 16; ++i)
    o[i] = bf16b(fmaxf((v[i] - mu) * rs * ga[i] + be[i], 0.f));
  lds_put16(dst, o, l, transp);
}

// ---- whole tree: 2 phases, 1 cross-block hop; 32 blocks x 512 thr ----
// Phase A per block: 32 leaves -> 16 L9 -> 8 L8 -> 4 L7 -> 2 L6 -> 1 L5.
// Slots: CW/out L9: 0..15; L8: 16..23; L7: 24..27; L6: 28,29; L5: 30;
//        leaf staging: 31+2w, 32+2w (wave-private). Peak 47 tiles.
// Phase B (block 0): F[32] -> slots 0..31; CW' L4: 32..47; L3: 48..55;
//        L2: 56..59; L1: 60,61; L0: 62. Peak 63 tiles.
__global__ __launch_bounds__(512) void k_tree2(
    const int* __restrict__ wid, const float* __restrict__ emb,
    const float* __restrict__ Ww, const float* __restrict__ Wb,
    const float* __restrict__ gamma, const float* __restrict__ beta,
    const float* __restrict__ Pw, const float* __restrict__ Pb,
    const int* __restrict__ label, unsigned* __restrict__ h5u,
    unsigned* __restrict__ h5f, float* __restrict__ out) {
  extern __shared__ __align__(16) short pool[];   // 63 tiles
  const int u = threadIdx.x, blk = blockIdx.x;
  const int wv = u >> 6, l = u & 63;
  NodeParams P = load_params(Ww, Wb, gamma, beta, l);

  // ---- phase A ----
  // CW prep. Pre-barrier-consumed slots (L9 2w,2w+1; L8 16+w) are prepped by
  // their consuming wave; post-barrier slots (24..30) by waves 0..6.
  cw_prep(pool + (2 * wv) * TILEB,
          emb + (size_t)wid[511 + 16 * blk + 2 * wv] * 1024, P, l);
  cw_prep(pool + (2 * wv + 1) * TILEB,
          emb + (size_t)wid[512 + 16 * blk + 2 * wv] * 1024, P, l);
  cw_prep(pool + (16 + wv) * TILEB,
          emb + (size_t)wid[255 + 8 * blk + wv] * 1024, P, l);
  if (wv < 4)
    cw_prep(pool + (24 + wv) * TILEB,
            emb + (size_t)wid[127 + 4 * blk + wv] * 1024, P, l);
  else if (wv < 6)
    cw_prep(pool + (28 + (wv - 4)) * TILEB,
            emb + (size_t)wid[63 + 2 * blk + (wv - 4)] * 1024, P, l);
  else if (wv == 6)
    cw_prep(pool + 30 * TILEB, emb + (size_t)wid[31 + blk] * 1024, P, l);

  // per-wave barrier-free chain: 4 leaves -> 2x L9 -> L8
  {
    short* Lf0 = pool + (31 + 2 * wv) * TILEB;
    short* Lf1 = pool + (32 + 2 * wv) * TILEB;
    const int lb = 1023 + 32 * blk + 4 * wv;
    leaf_ln(Lf0, emb + (size_t)wid[lb] * 1024, gamma, beta, l, false);
    leaf_ln(Lf1, emb + (size_t)wid[lb + 1] * 1024, gamma, beta, l, true);
    node2(Lf0, Lf1, pool + (2 * wv) * TILEB, P, l, pool + (2 * wv) * TILEB,
          false, nullptr);                              // L9_{2w} (left)
    leaf_ln(Lf0, emb + (size_t)wid[lb + 2] * 1024, gamma, beta, l, false);
    leaf_ln(Lf1, emb + (size_t)wid[lb + 3] * 1024, gamma, beta, l, true);
    node2(Lf0, Lf1, pool + (2 * wv + 1) * TILEB, P, l,
          pool + (2 * wv + 1) * TILEB, true, nullptr);  // L9_{2w+1} (right)
    node2(pool + (2 * wv) * TILEB, pool + (2 * wv + 1) * TILEB,
          pool + (16 + wv) * TILEB, P, l, pool + (16 + wv) * TILEB,
          (wv & 1) != 0, nullptr);                      // L8_w
  }
  __syncthreads();
  if (wv < 4)
    node2(pool + (16 + 2 * wv) * TILEB, pool + (17 + 2 * wv) * TILEB,
          pool + (24 + wv) * TILEB, P, l, pool + (24 + wv) * TILEB,
          (wv & 1) != 0, nullptr);                      // L7
  __syncthreads();
  if (wv < 2)
    node2(pool + (24 + 2 * wv) * TILEB, pool + (25 + 2 * wv) * TILEB,
          pool + (28 + wv) * TILEB, P, l, pool + (28 + wv) * TILEB,
          (wv & 1) != 0, nullptr);                      // L6
  __syncthreads();
  if (wv == 0)
    node2(pool + 28 * TILEB, pool + 29 * TILEB, pool + 30 * TILEB, P, l,
          pool + 30 * TILEB, false, nullptr);           // L5 (normal out)
  __syncthreads();
  emit512(h5u + (size_t)blk * 512, pool + 30 * TILEB, u);
  asm volatile("s_waitcnt vmcnt(0)" ::: "memory");
  __syncthreads();
  if (u == 0) flag_set(h5f + blk);

  if (blk != 0) return;
  // ---- phase B (block 0): L4..L0 + head ----
  // CW' prep before flag wait (independent of producers).
  cw_prep(pool + (32 + 2 * wv) * TILEB, emb + (size_t)wid[15 + 2 * wv] * 1024,
          P, l);
  cw_prep(pool + (33 + 2 * wv) * TILEB, emb + (size_t)wid[16 + 2 * wv] * 1024,
          P, l);
  cw_prep(pool + (48 + wv) * TILEB, emb + (size_t)wid[7 + wv] * 1024, P, l);
  if (wv < 4)
    cw_prep(pool + (56 + wv) * TILEB, emb + (size_t)wid[3 + wv] * 1024, P, l);
  else if (wv < 6)
    cw_prep(pool + (60 + (wv - 4)) * TILEB,
            emb + (size_t)wid[1 + (wv - 4)] * 1024, P, l);
  else if (wv == 6)
    cw_prep(pool + 62 * TILEB, emb + (size_t)wid[0] * 1024, P, l);
  if (u < 32) flag_wait(h5f + u);
  __syncthreads();
  // fetch h5 tiles: wave w -> F slots 4w..4w+3; odd local = right = transp
  #pragma unroll
  for (int q = 0; q < 4; ++q)
    fetch_tile(pool + (4 * wv + q) * TILEB, h5u + (size_t)(4 * wv + q) * 512,
               l, (q & 1) != 0);
  // per-wave chain: 2x L4 -> L3 (all same-wave data)
  node2(pool + (4 * wv) * TILEB, pool + (4 * wv + 1) * TILEB,
        pool + (32 + 2 * wv) * TILEB, P, l, pool + (32 + 2 * wv) * TILEB,
        false, nullptr);                                // L4_{2w} (left)
  node2(pool + (4 * wv + 2) * TILEB, pool + (4 * wv + 3) * TILEB,
        pool + (33 + 2 * wv) * TILEB, P, l, pool + (33 + 2 * wv) * TILEB,
        true, nullptr);                                 // L4_{2w+1} (right)
  node2(pool + (32 + 2 * wv) * TILEB, pool + (33 + 2 * wv) * TILEB,
        pool + (48 + wv) * TILEB, P, l, pool + (48 + wv) * TILEB,
        (wv & 1) != 0, nullptr);                        // L3_w
  __syncthreads();
  if (wv < 4)
    node2(pool + (48 + 2 * wv) * TILEB, pool + (49 + 2 * wv) * TILEB,
          pool + (56 + wv) * TILEB, P, l, pool + (56 + wv) * TILEB,
          (wv & 1) != 0, nullptr);                      // L2
  __syncthreads();
  if (wv < 2)
    node2(pool + (56 + 2 * wv) * TILEB, pool + (57 + 2 * wv) * TILEB,
          pool + (60 + wv) * TILEB, P, l, pool + (60 + wv) * TILEB,
          (wv & 1) != 0, nullptr);                      // L1
  __syncthreads();
  float* rootf = (float*)pool;            // tiles 0,1 dead (F consumed by L4)
  float* lred = (float*)pool + 1024;      // still in dead tile region
  if (wv == 0)
    node2(pool + 60 * TILEB, pool + 61 * TILEB, pool + 62 * TILEB, P, l,
          nullptr, false, rootf);                       // L0 -> fp32 root
  __syncthreads();
  // head: wave wv handles classes wv and wv+8
  #pragma unroll
  for (int q = 0; q < 2; ++q) {
    const int c = wv + 8 * q;
    if (c < 10) {
      float p = 0.f;
      #pragma unroll
      for (int t = 0; t < 4; ++t) {
        float4 r4 = *(const float4*)&rootf[l * 16 + t * 4];
        float4 w4 = *(const float4*)&Pw[c * 1024 + l * 16 + t * 4];
        p += r4.x * w4.x + r4.y * w4.y + r4.z * w4.z + r4.w * w4.w;
      }
      #pragma unroll
      for (int off = 32; off; off >>= 1) p += __shfl_xor(p, off);
      if (l == 0) lred[c] = p + Pb[c];
    }
  }
  __syncthreads();
  if (u == 0) {
    float mmax = lred[0];
    int am = 0;
    #pragma unroll
    for (int c = 1; c < 10; ++c)
      if (lred[c] > mmax) { mmax = lred[c]; am = c; }
    float sum = 0.f;
    #pragma unroll
    for (int c = 0; c < 10; ++c) sum += expf(lred[c] - mmax);
    const float loss = -(lred[label[0]] - mmax - logf(sum));
    out[0] = (float)am;
    out[1] = loss;
  }
}

extern "C" void kernel_launch(void* const* d_in, const int* in_sizes, int n_in,
                              void* d_out, int out_size, void* d_ws, size_t ws_size,
                              hipStream_t stream) {
  const int* wid = (const int*)d_in[0];
  const int* label = (const int*)d_in[1];
  const float* emb = (const float*)d_in[2];
  const float* Ww = (const float*)d_in[3];
  const float* Wb = (const float*)d_in[4];
  const float* g = (const float*)d_in[5];
  const float* b = (const float*)d_in[6];
  const float* Pw = (const float*)d_in[7];
  const float* Pb = (const float*)d_in[8];
  float* out = (float*)d_out;

  unsigned* h5u = (unsigned*)d_ws;          // 32 tiles x 512 u32
  unsigned* h5f = h5u + 32 * 512;           // 32 flags (MAGIC-keyed, no memset)

  const size_t SMEM = 63 * TILEB * sizeof(short);   // 161,280 B
  (void)hipFuncSetAttribute((const void*)k_tree2,
                            hipFuncAttributeMaxDynamicSharedMemorySize,
                            (int)SMEM);
  k_tree2<<<32, 512, SMEM, stream>>>(wid, emb, Ww, Wb, g, b, Pw, Pb, label,
                                     h5u, h5f, out);
}

// Round 11
// 28.111 us; speedup vs baseline: 1.2702x; 1.2702x over previous
//
#include <hip/hip_runtime.h>
#include <hip/hip_bf16.h>

#define LN_EPS 1e-5f
#define TSB 40                 // LDS tile row stride in bf16 (80B, 16B-aligned)
#define TILEB (32 * TSB)       // shorts per tile

typedef __attribute__((ext_vector_type(8))) short bf16x8;
typedef __attribute__((ext_vector_type(4))) short s16x4;
typedef __attribute__((ext_vector_type(16))) float f32x16;

__device__ __forceinline__ short bf16b(float f) {
  return __builtin_bit_cast(short, __float2bfloat16(f));
}

__device__ __forceinline__ void wave_reduce2(float& s1, float& s2) {
  #pragma unroll
  for (int off = 32; off; off >>= 1) {
    s1 += __shfl_xor(s1, off);
    s2 += __shfl_xor(s2, off);
  }
}

// A-frag/B-frag read from a row-major-[32][TSB] LDS tile.
// Normal tile -> A-operand (lane m holds A[m][k]); transposed tile -> B-operand.
__device__ __forceinline__ bf16x8 frag_ld(const short* t, int l, int k0) {
  return *(const bf16x8*)&t[(l & 31) * TSB + ((l >> 5) << 3) + k0];
}

__device__ __forceinline__ int cd_row(int r, int l) {
  return (r & 3) + 8 * (r >> 2) + 4 * (l >> 5);   // verified C/D mapping
}

// Transposed C/D store: per q, rows 8q+4*(l>>5)+(0..3) are contiguous -> b64.
__device__ __forceinline__ void cd_store_t(short* t, int l, const f32x16 d) {
  const int col = l & 31, h4 = 4 * (l >> 5);
  #pragma unroll
  for (int q = 0; q < 4; ++q) {
    s16x4 p;
    p[0] = bf16b(d[4 * q + 0]);
    p[1] = bf16b(d[4 * q + 1]);
    p[2] = bf16b(d[4 * q + 2]);
    p[3] = bf16b(d[4 * q + 3]);
    *(s16x4*)&t[col * TSB + 8 * q + h4] = p;
  }
}

__device__ __forceinline__ void cd_store(short* t, int l, const f32x16 d,
                                         bool transp) {
  if (transp) {
    cd_store_t(t, l, d);
  } else {
    const int col = l & 31;
    #pragma unroll
    for (int r = 0; r < 16; ++r) t[cd_row(r, l) * TSB + col] = bf16b(d[r]);
  }
}

struct NodeParams {
  bf16x8 w0, w1;        // Ww^T B-fragments (k0=0,16)
  float wb;             // Wb[col]
  float ga[16], be[16]; // gamma/beta at this lane's 16 C/D positions
};

__device__ __forceinline__ NodeParams load_params(const float* __restrict__ Ww,
    const float* __restrict__ Wb, const float* __restrict__ gamma,
    const float* __restrict__ beta, int l) {
  NodeParams P;
  const int n = l & 31, kh = (l >> 5) * 8;
  float w[8];
  *(float4*)&w[0] = *(const float4*)&Ww[n * 32 + kh];
  *(float4*)&w[4] = *(const float4*)&Ww[n * 32 + kh + 4];
  #pragma unroll
  for (int i = 0; i < 8; ++i) P.w0[i] = bf16b(w[i]);
  *(float4*)&w[0] = *(const float4*)&Ww[n * 32 + kh + 16];
  *(float4*)&w[4] = *(const float4*)&Ww[n * 32 + kh + 20];
  #pragma unroll
  for (int i = 0; i < 8; ++i) P.w1[i] = bf16b(w[i]);
  P.wb = Wb[n];
  #pragma unroll
  for (int r = 0; r < 16; ++r) {
    const int idx = cd_row(r, l) * 32 + n;
    P.ga[r] = gamma[idx];
    P.be[r] = beta[idx];
  }
  return P;
}

__device__ __forceinline__ f32x16 mm32(const short* A, const short* B, int l) {
  f32x16 acc = {};
  acc = __builtin_amdgcn_mfma_f32_32x32x16_bf16(frag_ld(A, l, 0),
                                                frag_ld(B, l, 0), acc, 0, 0, 0);
  acc = __builtin_amdgcn_mfma_f32_32x32x16_bf16(frag_ld(A, l, 16),
                                                frag_ld(B, l, 16), acc, 0, 0, 0);
  return acc;
}

// fp32 global tile [32][32] -> LDS bf16, normal or transposed; one wave
__device__ __forceinline__ void stage_f32(short* dst,
                                          const float* __restrict__ src, int l,
                                          bool transp) {
  float v[16];
  #pragma unroll
  for (int q = 0; q < 4; ++q)
    *(float4*)&v[q * 4] = *(const float4*)&src[l * 16 + q * 4];
  const int row = l >> 1, c0 = (l & 1) * 16;
  if (transp) {
    #pragma unroll
    for (int i = 0; i < 16; ++i) dst[(c0 + i) * TSB + row] = bf16b(v[i]);
  } else {
    #pragma unroll
    for (int i = 0; i < 8; ++i) {
      unsigned lo = (unsigned short)bf16b(v[2 * i]);
      unsigned hi = (unsigned short)bf16b(v[2 * i + 1]);
      ((unsigned*)dst)[row * (TSB / 2) + (c0 >> 1) + i] = lo | (hi << 16);
    }
  }
}

// CW = C @ Ww^T precompute: stage C normal, 2 MFMA with register Ww^T frags,
// store transposed (B-operand layout) back into the same slot. Same-wave
// in-order LDS (proven cd_store->frag_ld pattern).
__device__ __forceinline__ void cw_prep(short* slot,
                                        const float* __restrict__ src,
                                        const NodeParams& P, int l) {
  stage_f32(slot, src, l, false);
  f32x16 cw = {};
  cw = __builtin_amdgcn_mfma_f32_32x32x16_bf16(frag_ld(slot, l, 0), P.w0, cw, 0, 0, 0);
  cw = __builtin_amdgcn_mfma_f32_32x32x16_bf16(frag_ld(slot, l, 16), P.w1, cw, 0, 0, 0);
  cd_store_t(slot, l, cw);
}

// Tree node, 2 dependent matmuls: X = (L@R)@CW + Wb; LN+ReLU.
// A = left child (normal), Bt = right child (transposed), CWt = C@Ww^T
// (transposed). T1 scratch overwrites A. Output -> dst (or fp32 fout).
__device__ __forceinline__ void node2(short* A, short* Bt, short* CWt,
                                      const NodeParams& P, int l, short* dst,
                                      bool transpOut, float* fout) {
  f32x16 t1 = mm32(A, Bt, l);
  cd_store(A, l, t1, false);            // T1 (normal, A-layout) into A slot
  f32x16 x = mm32(A, CWt, l);           // X = T1 @ CW
  float s1 = 0.f, s2 = 0.f;
  #pragma unroll
  for (int r = 0; r < 16; ++r) {
    x[r] += P.wb;
    s1 += x[r];
    s2 += x[r] * x[r];
  }
  wave_reduce2(s1, s2);
  const float mu = s1 * (1.f / 1024.f);
  const float rs = rsqrtf(s2 * (1.f / 1024.f) - mu * mu + LN_EPS);
  #pragma unroll
  for (int r = 0; r < 16; ++r)
    x[r] = fmaxf((x[r] - mu) * rs * P.ga[r] + P.be[r], 0.f);
  if (fout) {
    #pragma unroll
    for (int r = 0; r < 16; ++r) fout[cd_row(r, l) * 32 + (l & 31)] = x[r];
  } else {
    cd_store(dst, l, x, transpOut);
  }
}

// bf16 global compact tile [32][32] -> LDS, normal or transposed; one wave
__device__ __forceinline__ void stage_bf16(short* dst,
                                           const short* __restrict__ src, int l,
                                           bool transp) {
  short v[16];
  *(bf16x8*)&v[0] = *(const bf16x8*)&src[l * 16];
  *(bf16x8*)&v[8] = *(const bf16x8*)&src[l * 16 + 8];
  const int row = l >> 1, c0 = (l & 1) * 16;
  if (transp) {
    #pragma unroll
    for (int i = 0; i < 16; ++i) dst[(c0 + i) * TSB + row] = v[i];
  } else {
    #pragma unroll
    for (int i = 0; i < 8; ++i) {
      unsigned lo = (unsigned short)v[2 * i];
      unsigned hi = (unsigned short)v[2 * i + 1];
      ((unsigned*)dst)[row * (TSB / 2) + (c0 >> 1) + i] = lo | (hi << 16);
    }
  }
}

// LDS normal tile -> global compact bf16 [32][32]; threads u<128, 1 b128 each
__device__ __forceinline__ void copy_out(short* __restrict__ dst, const short* t,
                                         int u) {
  if (u < 128) {
    const int row = u >> 2, c0 = (u & 3) * 8;
    *(bf16x8*)&dst[row * 32 + c0] = *(const bf16x8*)&t[row * TSB + c0];
  }
}

// leaf: load fp32 tile, LN+ReLU in-wave, write bf16 with parity layout
__device__ __forceinline__ void leaf_ln(short* dst, const float* __restrict__ src,
                                        const float* __restrict__ gamma,
                                        const float* __restrict__ beta, int l,
                                        bool transp) {
  float v[16], ga[16], be[16];
  #pragma unroll
  for (int q = 0; q < 4; ++q) {
    *(float4*)&v[q * 4] = *(const float4*)&src[l * 16 + q * 4];
    *(float4*)&ga[q * 4] = *(const float4*)&gamma[l * 16 + q * 4];
    *(float4*)&be[q * 4] = *(const float4*)&beta[l * 16 + q * 4];
  }
  float s1 = 0.f, s2 = 0.f;
  #pragma unroll
  for (int i = 0; i < 16; ++i) { s1 += v[i]; s2 += v[i] * v[i]; }
  wave_reduce2(s1, s2);
  const float mu = s1 * (1.f / 1024.f);
  const float rs = rsqrtf(s2 * (1.f / 1024.f) - mu * mu + LN_EPS);
  float o[16];
  #pragma unroll
  for (int i = 0; i < 16; ++i)
    o[i] = fmaxf((v[i] - mu) * rs * ga[i] + be[i], 0.f);
  const int row = l >> 1, c0 = (l & 1) * 16;
  if (transp) {
    #pragma unroll
    for (int i = 0; i < 16; ++i) dst[(c0 + i) * TSB + row] = bf16b(o[i]);
  } else {
    #pragma unroll
    for (int i = 0; i < 8; ++i) {
      unsigned lo = (unsigned short)bf16b(o[2 * i]);
      unsigned hi = (unsigned short)bf16b(o[2 * i + 1]);
      ((unsigned*)dst)[row * (TSB / 2) + (c0 >> 1) + i] = lo | (hi << 16);
    }
  }
}

// ---- K1: 8 leaves + 4xL9 + 2xL8 + 1xL7; 128 blocks x 512 thr ----
__global__ __launch_bounds__(512) void k_bot7(
    const int* __restrict__ wid, const float* __restrict__ emb,
    const float* __restrict__ Ww, const float* __restrict__ Wb,
    const float* __restrict__ gamma, const float* __restrict__ beta,
    short* __restrict__ h7) {
  __shared__ __align__(16) short pool[15 * TILEB];
  const int u = threadIdx.x, blk = blockIdx.x;
  const int wv = u >> 6, l = u & 63;
  NodeParams P = load_params(Ww, Wb, gamma, beta, l);
  // leaves: one per wave -> slots 0..7; odd position = right = transposed
  leaf_ln(pool + wv * TILEB, emb + (size_t)wid[1023 + 8 * blk + wv] * 1024,
          gamma, beta, l, (wv & 1) != 0);
  // CW tiles (transposed B-operands): L9 -> 8..11, L8 -> 12..13, L7 -> 14
  if (wv < 4)
    cw_prep(pool + (8 + wv) * TILEB,
            emb + (size_t)wid[511 + 4 * blk + wv] * 1024, P, l);
  else if (wv < 6)
    cw_prep(pool + (8 + wv) * TILEB,
            emb + (size_t)wid[255 + 2 * blk + (wv - 4)] * 1024, P, l);
  else if (wv == 6)
    cw_prep(pool + 14 * TILEB, emb + (size_t)wid[127 + blk] * 1024, P, l);
  __syncthreads();
  // L9: 4 nodes on waves 0..3; out -> CW slot, parity by node index
  if (wv < 4)
    node2(pool + 2 * wv * TILEB, pool + (2 * wv + 1) * TILEB,
          pool + (8 + wv) * TILEB, P, l, pool + (8 + wv) * TILEB,
          (wv & 1) != 0, nullptr);
  __syncthreads();
  // L8: 2 nodes on waves 0,1
  if (wv < 2)
    node2(pool + (8 + 2 * wv) * TILEB, pool + (9 + 2 * wv) * TILEB,
          pool + (12 + wv) * TILEB, P, l, pool + (12 + wv) * TILEB,
          (wv & 1) != 0, nullptr);
  __syncthreads();
  // L7: 1 node on wave 0, out normal -> slot 14
  if (wv == 0)
    node2(pool + 12 * TILEB, pool + 13 * TILEB, pool + 14 * TILEB, P, l,
          pool + 14 * TILEB, false, nullptr);
  __syncthreads();
  copy_out(h7 + (size_t)blk * 1024, pool + 14 * TILEB, u);
}

// ---- K2: L6 + L5 + L4; 16 blocks x 512 thr ----
__global__ __launch_bounds__(512) void k_mid16(
    const int* __restrict__ wid, const float* __restrict__ emb,
    const float* __restrict__ Ww, const float* __restrict__ Wb,
    const float* __restrict__ gamma, const float* __restrict__ beta,
    const short* __restrict__ hin, short* __restrict__ hout) {
  __shared__ __align__(16) short pool[15 * TILEB];
  const int u = threadIdx.x, blk = blockIdx.x;
  const int wv = u >> 6, l = u & 63;
  NodeParams P = load_params(Ww, Wb, gamma, beta, l);
  // children: wave w stages h7 tile 8*blk+w -> slot w, parity by position
  stage_bf16(pool + wv * TILEB, hin + (size_t)(8 * blk + wv) * 1024, l,
             (wv & 1) != 0);
  // CW tiles: L6 (base 63) -> 8..11, L5 (base 31) -> 12..13, L4 (base 15) -> 14
  if (wv < 4)
    cw_prep(pool + (8 + wv) * TILEB,
            emb + (size_t)wid[63 + 4 * blk + wv] * 1024, P, l);
  else if (wv < 6)
    cw_prep(pool + (8 + wv) * TILEB,
            emb + (size_t)wid[31 + 2 * blk + (wv - 4)] * 1024, P, l);
  else if (wv == 6)
    cw_prep(pool + 14 * TILEB, emb + (size_t)wid[15 + blk] * 1024, P, l);
  __syncthreads();
  // L6: 4 nodes on waves 0..3
  if (wv < 4)
    node2(pool + 2 * wv * TILEB, pool + (2 * wv + 1) * TILEB,
          pool + (8 + wv) * TILEB, P, l, pool + (8 + wv) * TILEB,
          (wv & 1) != 0, nullptr);
  __syncthreads();
  // L5: 2 nodes on waves 0,1
  if (wv < 2)
    node2(pool + (8 + 2 * wv) * TILEB, pool + (9 + 2 * wv) * TILEB,
          pool + (12 + wv) * TILEB, P, l, pool + (12 + wv) * TILEB,
          (wv & 1) != 0, nullptr);
  __syncthreads();
  // L4: 1 node on wave 0, out normal -> slot 14
  if (wv == 0)
    node2(pool + 12 * TILEB, pool + 13 * TILEB, pool + 14 * TILEB, P, l,
          pool + 14 * TILEB, false, nullptr);
  __syncthreads();
  copy_out(hout + (size_t)blk * 1024, pool + 14 * TILEB, u);
}

// ---- K3: L3 + L2 + L1 + L0 + head; 1 block x 512 thr ----
__global__ __launch_bounds__(512) void k_top2(
    const int* __restrict__ wid, const float* __restrict__ emb,
    const float* __restrict__ Ww, const float* __restrict__ Wb,
    const float* __restrict__ gamma, const float* __restrict__ beta,
    const float* __restrict__ Pw, const float* __restrict__ Pb,
    const int* __restrict__ label, const short* __restrict__ hin,
    float* __restrict__ out) {
  __shared__ __align__(16) short pool[31 * TILEB];
  __shared__ float rootf[1024];
  __shared__ float lred[10];
  const int u = threadIdx.x;
  const int wv = u >> 6, l = u & 63;
  NodeParams P = load_params(Ww, Wb, gamma, beta, l);
  // wave w: stage its own children (2w normal, 2w+1 transp) + own L3 CW ->
  // L3 is fully same-wave, no barrier needed before it.
  stage_bf16(pool + 2 * wv * TILEB, hin + (size_t)(2 * wv) * 1024, l, false);
  stage_bf16(pool + (2 * wv + 1) * TILEB, hin + (size_t)(2 * wv + 1) * 1024, l,
             true);
  cw_prep(pool + (16 + wv) * TILEB, emb + (size_t)wid[7 + wv] * 1024, P, l);
  // L3: 8 nodes, one per wave (same-wave children + CW)
  node2(pool + 2 * wv * TILEB, pool + (2 * wv + 1) * TILEB,
        pool + (16 + wv) * TILEB, P, l, pool + (16 + wv) * TILEB,
        (wv & 1) != 0, nullptr);
  // extra CW preps (consumed post-barrier): L2 -> 24..27, L1 -> 28,29, L0 -> 30
  if (wv < 4)
    cw_prep(pool + (24 + wv) * TILEB, emb + (size_t)wid[3 + wv] * 1024, P, l);
  else if (wv < 6)
    cw_prep(pool + (28 + (wv - 4)) * TILEB,
            emb + (size_t)wid[1 + (wv - 4)] * 1024, P, l);
  else if (wv == 6)
    cw_prep(pool + 30 * TILEB, emb + (size_t)wid[0] * 1024, P, l);
  __syncthreads();
  // L2: 4 nodes on waves 0..3
  if (wv < 4)
    node2(pool + (16 + 2 * wv) * TILEB, pool + (17 + 2 * wv) * TILEB,
          pool + (24 + wv) * TILEB, P, l, pool + (24 + wv) * TILEB,
          (wv & 1) != 0, nullptr);
  __syncthreads();
  // L1: 2 nodes on waves 0,1
  if (wv < 2)
    node2(pool + (24 + 2 * wv) * TILEB, pool + (25 + 2 * wv) * TILEB,
          pool + (28 + wv) * TILEB, P, l, pool + (28 + wv) * TILEB,
          (wv & 1) != 0, nullptr);
  __syncthreads();
  // L0 -> fp32 root
  if (wv == 0)
    node2(pool + 28 * TILEB, pool + 29 * TILEB, pool + 30 * TILEB, P, l,
          nullptr, false, rootf);
  __syncthreads();
  // head: wave wv handles classes wv and wv+8
  #pragma unroll
  for (int q = 0; q < 2; ++q) {
    const int c = wv + 8 * q;
    if (c < 10) {
      float p = 0.f;
      #pragma unroll
      for (int t = 0; t < 4; ++t) {
        float4 r4 = *(const float4*)&rootf[l * 16 + t * 4];
        float4 w4 = *(const float4*)&Pw[c * 1024 + l * 16 + t * 4];
        p += r4.x * w4.x + r4.y * w4.y + r4.z * w4.z + r4.w * w4.w;
      }
      #pragma unroll
      for (int off = 32; off; off >>= 1) p += __shfl_xor(p, off);
      if (l == 0) lred[c] = p + Pb[c];
    }
  }
  __syncthreads();
  if (u == 0) {
    float mmax = lred[0];
    int am = 0;
    #pragma unroll
    for (int c = 1; c < 10; ++c)
      if (lred[c] > mmax) { mmax = lred[c]; am = c; }
    float sum = 0.f;
    #pragma unroll
    for (int c = 0; c < 10; ++c) sum += expf(lred[c] - mmax);
    const float loss = -(lred[label[0]] - mmax - logf(sum));
    out[0] = (float)am;
    out[1] = loss;
  }
}

extern "C" void kernel_launch(void* const* d_in, const int* in_sizes, int n_in,
                              void* d_out, int out_size, void* d_ws, size_t ws_size,
                              hipStream_t stream) {
  const int* wid = (const int*)d_in[0];
  const int* label = (const int*)d_in[1];
  const float* emb = (const float*)d_in[2];
  const float* Ww = (const float*)d_in[3];
  const float* Wb = (const float*)d_in[4];
  const float* g = (const float*)d_in[5];
  const float* b = (const float*)d_in[6];
  const float* Pw = (const float*)d_in[7];
  const float* Pb = (const float*)d_in[8];
  float* out = (float*)d_out;

  short* h7 = (short*)d_ws;          // 128 tiles x 1024 bf16
  short* h4 = h7 + 128 * 1024;       // 16 tiles

  k_bot7<<<128, 512, 0, stream>>>(wid, emb, Ww, Wb, g, b, h7);
  k_mid16<<<16, 512, 0, stream>>>(wid, emb, Ww, Wb, g, b, h7, h4);
  k_top2<<<1, 512, 0, stream>>>(wid, emb, Ww, Wb, g, b, Pw, Pb, label, h4, out);
}

// Round 12
// 27.181 us; speedup vs baseline: 1.3137x; 1.0342x over previous
//
#include <hip/hip_runtime.h>
#include <hip/hip_bf16.h>

#define LN_EPS 1e-5f
#define TSB 40                 // LDS tile row stride in bf16 (80B, 16B-aligned)
#define TILEB (32 * TSB)       // shorts per tile

typedef __attribute__((ext_vector_type(8))) short bf16x8;
typedef __attribute__((ext_vector_type(4))) short s16x4;
typedef __attribute__((ext_vector_type(4))) unsigned u32x4;
typedef __attribute__((ext_vector_type(16))) float f32x16;

__device__ __forceinline__ short bf16b(float f) {
  return __builtin_bit_cast(short, __float2bfloat16(f));
}

__device__ __forceinline__ void wave_reduce2(float& s1, float& s2) {
  #pragma unroll
  for (int off = 32; off; off >>= 1) {
    s1 += __shfl_xor(s1, off);
    s2 += __shfl_xor(s2, off);
  }
}

// A-frag/B-frag read from a row-major-[32][TSB] LDS tile.
// Normal tile -> A-operand (lane m holds A[m][k]); transposed tile -> B-operand.
__device__ __forceinline__ bf16x8 frag_ld(const short* t, int l, int k0) {
  return *(const bf16x8*)&t[(l & 31) * TSB + ((l >> 5) << 3) + k0];
}

__device__ __forceinline__ int cd_row(int r, int l) {
  return (r & 3) + 8 * (r >> 2) + 4 * (l >> 5);   // verified C/D mapping
}

// Transposed C/D store: per q, rows 8q+4*(l>>5)+(0..3) are contiguous -> b64.
__device__ __forceinline__ void cd_store_t(short* t, int l, const f32x16 d) {
  const int col = l & 31, h4 = 4 * (l >> 5);
  #pragma unroll
  for (int q = 0; q < 4; ++q) {
    s16x4 p;
    p[0] = bf16b(d[4 * q + 0]);
    p[1] = bf16b(d[4 * q + 1]);
    p[2] = bf16b(d[4 * q + 2]);
    p[3] = bf16b(d[4 * q + 3]);
    *(s16x4*)&t[col * TSB + 8 * q + h4] = p;
  }
}

__device__ __forceinline__ void cd_store(short* t, int l, const f32x16 d,
                                         bool transp) {
  if (transp) {
    cd_store_t(t, l, d);
  } else {
    const int col = l & 31;
    #pragma unroll
    for (int r = 0; r < 16; ++r) t[cd_row(r, l) * TSB + col] = bf16b(d[r]);
  }
}

struct NodeParams {
  bf16x8 w0, w1;        // Ww^T B-fragments (k0=0,16)
  float wb;             // Wb[col]
  float ga[16], be[16]; // gamma/beta at this lane's 16 C/D positions
};

__device__ __forceinline__ NodeParams load_params(const float* __restrict__ Ww,
    const float* __restrict__ Wb, const float* __restrict__ gamma,
    const float* __restrict__ beta, int l) {
  NodeParams P;
  const int n = l & 31, kh = (l >> 5) * 8;
  float w[8];
  *(float4*)&w[0] = *(const float4*)&Ww[n * 32 + kh];
  *(float4*)&w[4] = *(const float4*)&Ww[n * 32 + kh + 4];
  #pragma unroll
  for (int i = 0; i < 8; ++i) P.w0[i] = bf16b(w[i]);
  *(float4*)&w[0] = *(const float4*)&Ww[n * 32 + kh + 16];
  *(float4*)&w[4] = *(const float4*)&Ww[n * 32 + kh + 20];
  #pragma unroll
  for (int i = 0; i < 8; ++i) P.w1[i] = bf16b(w[i]);
  P.wb = Wb[n];
  #pragma unroll
  for (int r = 0; r < 16; ++r) {
    const int idx = cd_row(r, l) * 32 + n;
    P.ga[r] = gamma[idx];
    P.be[r] = beta[idx];
  }
  return P;
}

// exchange: a's hi-32-lane values <-> b's lo-32-lane values (CDNA4 VALU)
__device__ __forceinline__ void pl32swap(unsigned& a, unsigned& b) {
  asm volatile("v_permlane32_swap_b32 %0, %1" : "+v"(a), "+v"(b));
}

// Convert T1^T MFMA output (lane l = row m=l&31 of T1 at cols
// {4h+0..3, 8+4h+0..3, 16+4h+0..3, 24+4h+0..3}, h=l>>5) into the two
// A-operand fragments of T1 (k0=0,16) fully in-register: pack bf16 pairs,
// then 4 permlane32_swap -- each swap yields BOTH halves' needed dwords.
__device__ __forceinline__ void t1t_to_afrags(const f32x16 t, bf16x8& f0,
                                              bf16x8& f1) {
  unsigned P[8];
  #pragma unroll
  for (int i = 0; i < 8; ++i)
    P[i] = (unsigned)(unsigned short)bf16b(t[2 * i]) |
           ((unsigned)(unsigned short)bf16b(t[2 * i + 1]) << 16);
  pl32swap(P[0], P[2]);   // P0 -> frag0.d0 (k 8h+0,1), P2 -> frag0.d2 (8h+4,5)
  pl32swap(P[1], P[3]);   // P1 -> frag0.d1, P3 -> frag0.d3
  pl32swap(P[4], P[6]);   // P4 -> frag1.d0, P6 -> frag1.d2
  pl32swap(P[5], P[7]);   // P5 -> frag1.d1, P7 -> frag1.d3
  u32x4 lo = {P[0], P[1], P[2], P[3]};
  u32x4 hi = {P[4], P[5], P[6], P[7]};
  f0 = __builtin_bit_cast(bf16x8, lo);
  f1 = __builtin_bit_cast(bf16x8, hi);
}

// Tree node, fully in-register chain: T1^T = R^T@L^T (swapped frag roles),
// permlane-convert to T1 A-frags, X = T1@CW + Wb, LN+ReLU -> dst/fout.
// An = left child (normal tile), Bt = right child (transposed), CWt = C@Ww^T.
// No scratch LDS writes at all.
__device__ __forceinline__ void node3(const short* An, const short* Bt,
                                      const short* CWt, const NodeParams& P,
                                      int l, short* dst, bool transpOut,
                                      float* fout) {
  bf16x8 rA0 = frag_ld(Bt, l, 0), rA1 = frag_ld(Bt, l, 16);   // A = R^T
  bf16x8 lB0 = frag_ld(An, l, 0), lB1 = frag_ld(An, l, 16);   // B = L^T
  bf16x8 cw0 = frag_ld(CWt, l, 0), cw1 = frag_ld(CWt, l, 16); // B = CW
  f32x16 t1t = {};
  t1t = __builtin_amdgcn_mfma_f32_32x32x16_bf16(rA0, lB0, t1t, 0, 0, 0);
  t1t = __builtin_amdgcn_mfma_f32_32x32x16_bf16(rA1, lB1, t1t, 0, 0, 0);
  bf16x8 a0, a1;
  t1t_to_afrags(t1t, a0, a1);
  f32x16 x = {};
  x = __builtin_amdgcn_mfma_f32_32x32x16_bf16(a0, cw0, x, 0, 0, 0);
  x = __builtin_amdgcn_mfma_f32_32x32x16_bf16(a1, cw1, x, 0, 0, 0);
  float s1 = 0.f, s2 = 0.f;
  #pragma unroll
  for (int r = 0; r < 16; ++r) {
    x[r] += P.wb;
    s1 += x[r];
    s2 += x[r] * x[r];
  }
  wave_reduce2(s1, s2);
  const float mu = s1 * (1.f / 1024.f);
  const float rs = rsqrtf(s2 * (1.f / 1024.f) - mu * mu + LN_EPS);
  #pragma unroll
  for (int r = 0; r < 16; ++r)
    x[r] = fmaxf((x[r] - mu) * rs * P.ga[r] + P.be[r], 0.f);
  if (fout) {
    #pragma unroll
    for (int r = 0; r < 16; ++r) fout[cd_row(r, l) * 32 + (l & 31)] = x[r];
  } else {
    cd_store(dst, l, x, transpOut);
  }
}

__device__ __forceinline__ f32x16 mm32(const short* A, const short* B, int l) {
  f32x16 acc = {};
  acc = __builtin_amdgcn_mfma_f32_32x32x16_bf16(frag_ld(A, l, 0),
                                                frag_ld(B, l, 0), acc, 0, 0, 0);
  acc = __builtin_amdgcn_mfma_f32_32x32x16_bf16(frag_ld(A, l, 16),
                                                frag_ld(B, l, 16), acc, 0, 0, 0);
  return acc;
}

// fp32 global tile [32][32] -> LDS bf16, normal or transposed; one wave
__device__ __forceinline__ void stage_f32(short* dst,
                                          const float* __restrict__ src, int l,
                                          bool transp) {
  float v[16];
  #pragma unroll
  for (int q = 0; q < 4; ++q)
    *(float4*)&v[q * 4] = *(const float4*)&src[l * 16 + q * 4];
  const int row = l >> 1, c0 = (l & 1) * 16;
  if (transp) {
    #pragma unroll
    for (int i = 0; i < 16; ++i) dst[(c0 + i) * TSB + row] = bf16b(v[i]);
  } else {
    #pragma unroll
    for (int i = 0; i < 8; ++i) {
      unsigned lo = (unsigned short)bf16b(v[2 * i]);
      unsigned hi = (unsigned short)bf16b(v[2 * i + 1]);
      ((unsigned*)dst)[row * (TSB / 2) + (c0 >> 1) + i] = lo | (hi << 16);
    }
  }
}

// CW = C @ Ww^T precompute: stage C normal, 2 MFMA with register Ww^T frags,
// store transposed (B-operand layout) back into the same slot. Same-wave
// in-order LDS (proven cd_store->frag_ld pattern).
__device__ __forceinline__ void cw_prep(short* slot,
                                        const float* __restrict__ src,
                                        const NodeParams& P, int l) {
  stage_f32(slot, src, l, false);
  f32x16 cw = {};
  cw = __builtin_amdgcn_mfma_f32_32x32x16_bf16(frag_ld(slot, l, 0), P.w0, cw, 0, 0, 0);
  cw = __builtin_amdgcn_mfma_f32_32x32x16_bf16(frag_ld(slot, l, 16), P.w1, cw, 0, 0, 0);
  cd_store_t(slot, l, cw);
}

// bf16 global compact tile [32][32] -> LDS, normal or transposed; one wave
__device__ __forceinline__ void stage_bf16(short* dst,
                                           const short* __restrict__ src, int l,
                                           bool transp) {
  short v[16];
  *(bf16x8*)&v[0] = *(const bf16x8*)&src[l * 16];
  *(bf16x8*)&v[8] = *(const bf16x8*)&src[l * 16 + 8];
  const int row = l >> 1, c0 = (l & 1) * 16;
  if (transp) {
    #pragma unroll
    for (int i = 0; i < 16; ++i) dst[(c0 + i) * TSB + row] = v[i];
  } else {
    #pragma unroll
    for (int i = 0; i < 8; ++i) {
      unsigned lo = (unsigned short)v[2 * i];
      unsigned hi = (unsigned short)v[2 * i + 1];
      ((unsigned*)dst)[row * (TSB / 2) + (c0 >> 1) + i] = lo | (hi << 16);
    }
  }
}

// LDS normal tile -> global compact bf16 [32][32]; threads u<128, 1 b128 each
__device__ __forceinline__ void copy_out(short* __restrict__ dst, const short* t,
                                         int u) {
  if (u < 128) {
    const int row = u >> 2, c0 = (u & 3) * 8;
    *(bf16x8*)&dst[row * 32 + c0] = *(const bf16x8*)&t[row * TSB + c0];
  }
}

// leaf: load fp32 tile, LN+ReLU in-wave, write bf16 with parity layout
__device__ __forceinline__ void leaf_ln(short* dst, const float* __restrict__ src,
                                        const float* __restrict__ gamma,
                                        const float* __restrict__ beta, int l,
                                        bool transp) {
  float v[16], ga[16], be[16];
  #pragma unroll
  for (int q = 0; q < 4; ++q) {
    *(float4*)&v[q * 4] = *(const float4*)&src[l * 16 + q * 4];
    *(float4*)&ga[q * 4] = *(const float4*)&gamma[l * 16 + q * 4];
    *(float4*)&be[q * 4] = *(const float4*)&beta[l * 16 + q * 4];
  }
  float s1 = 0.f, s2 = 0.f;
  #pragma unroll
  for (int i = 0; i < 16; ++i) { s1 += v[i]; s2 += v[i] * v[i]; }
  wave_reduce2(s1, s2);
  const float mu = s1 * (1.f / 1024.f);
  const float rs = rsqrtf(s2 * (1.f / 1024.f) - mu * mu + LN_EPS);
  float o[16];
  #pragma unroll
  for (int i = 0; i < 16; ++i)
    o[i] = fmaxf((v[i] - mu) * rs * ga[i] + be[i], 0.f);
  const int row = l >> 1, c0 = (l & 1) * 16;
  if (transp) {
    #pragma unroll
    for (int i = 0; i < 16; ++i) dst[(c0 + i) * TSB + row] = bf16b(o[i]);
  } else {
    #pragma unroll
    for (int i = 0; i < 8; ++i) {
      unsigned lo = (unsigned short)bf16b(o[2 * i]);
      unsigned hi = (unsigned short)bf16b(o[2 * i + 1]);
      ((unsigned*)dst)[row * (TSB / 2) + (c0 >> 1) + i] = lo | (hi << 16);
    }
  }
}

// ---- K1: 8 leaves + 4xL9 + 2xL8 + 1xL7; 128 blocks x 512 thr ----
__global__ __launch_bounds__(512) void k_bot7(
    const int* __restrict__ wid, const float* __restrict__ emb,
    const float* __restrict__ Ww, const float* __restrict__ Wb,
    const float* __restrict__ gamma, const float* __restrict__ beta,
    short* __restrict__ h7) {
  __shared__ __align__(16) short pool[15 * TILEB];
  const int u = threadIdx.x, blk = blockIdx.x;
  const int wv = u >> 6, l = u & 63;
  NodeParams P = load_params(Ww, Wb, gamma, beta, l);
  // leaves: one per wave -> slots 0..7; odd position = right = transposed
  leaf_ln(pool + wv * TILEB, emb + (size_t)wid[1023 + 8 * blk + wv] * 1024,
          gamma, beta, l, (wv & 1) != 0);
  // CW tiles (transposed B-operands): L9 -> 8..11, L8 -> 12..13, L7 -> 14
  if (wv < 4)
    cw_prep(pool + (8 + wv) * TILEB,
            emb + (size_t)wid[511 + 4 * blk + wv] * 1024, P, l);
  else if (wv < 6)
    cw_prep(pool + (8 + wv) * TILEB,
            emb + (size_t)wid[255 + 2 * blk + (wv - 4)] * 1024, P, l);
  else if (wv == 6)
    cw_prep(pool + 14 * TILEB, emb + (size_t)wid[127 + blk] * 1024, P, l);
  __syncthreads();
  // L9: 4 nodes on waves 0..3; out -> CW slot, parity by node index
  if (wv < 4)
    node3(pool + 2 * wv * TILEB, pool + (2 * wv + 1) * TILEB,
          pool + (8 + wv) * TILEB, P, l, pool + (8 + wv) * TILEB,
          (wv & 1) != 0, nullptr);
  __syncthreads();
  // L8: 2 nodes on waves 0,1
  if (wv < 2)
    node3(pool + (8 + 2 * wv) * TILEB, pool + (9 + 2 * wv) * TILEB,
          pool + (12 + wv) * TILEB, P, l, pool + (12 + wv) * TILEB,
          (wv & 1) != 0, nullptr);
  __syncthreads();
  // L7: 1 node on wave 0, out normal -> slot 14
  if (wv == 0)
    node3(pool + 12 * TILEB, pool + 13 * TILEB, pool + 14 * TILEB, P, l,
          pool + 14 * TILEB, false, nullptr);
  __syncthreads();
  copy_out(h7 + (size_t)blk * 1024, pool + 14 * TILEB, u);
}

// ---- K2: L6 + L5 + L4; 16 blocks x 512 thr ----
__global__ __launch_bounds__(512) void k_mid16(
    const int* __restrict__ wid, const float* __restrict__ emb,
    const float* __restrict__ Ww, const float* __restrict__ Wb,
    const float* __restrict__ gamma, const float* __restrict__ beta,
    const short* __restrict__ hin, short* __restrict__ hout) {
  __shared__ __align__(16) short pool[15 * TILEB];
  const int u = threadIdx.x, blk = blockIdx.x;
  const int wv = u >> 6, l = u & 63;
  NodeParams P = load_params(Ww, Wb, gamma, beta, l);
  // children: wave w stages h7 tile 8*blk+w -> slot w, parity by position
  stage_bf16(pool + wv * TILEB, hin + (size_t)(8 * blk + wv) * 1024, l,
             (wv & 1) != 0);
  // CW tiles: L6 (base 63) -> 8..11, L5 (base 31) -> 12..13, L4 (base 15) -> 14
  if (wv < 4)
    cw_prep(pool + (8 + wv) * TILEB,
            emb + (size_t)wid[63 + 4 * blk + wv] * 1024, P, l);
  else if (wv < 6)
    cw_prep(pool + (8 + wv) * TILEB,
            emb + (size_t)wid[31 + 2 * blk + (wv - 4)] * 1024, P, l);
  else if (wv == 6)
    cw_prep(pool + 14 * TILEB, emb + (size_t)wid[15 + blk] * 1024, P, l);
  __syncthreads();
  // L6: 4 nodes on waves 0..3
  if (wv < 4)
    node3(pool + 2 * wv * TILEB, pool + (2 * wv + 1) * TILEB,
          pool + (8 + wv) * TILEB, P, l, pool + (8 + wv) * TILEB,
          (wv & 1) != 0, nullptr);
  __syncthreads();
  // L5: 2 nodes on waves 0,1
  if (wv < 2)
    node3(pool + (8 + 2 * wv) * TILEB, pool + (9 + 2 * wv) * TILEB,
          pool + (12 + wv) * TILEB, P, l, pool + (12 + wv) * TILEB,
          (wv & 1) != 0, nullptr);
  __syncthreads();
  // L4: 1 node on wave 0, out normal -> slot 14
  if (wv == 0)
    node3(pool + 12 * TILEB, pool + 13 * TILEB, pool + 14 * TILEB, P, l,
          pool + 14 * TILEB, false, nullptr);
  __syncthreads();
  copy_out(hout + (size_t)blk * 1024, pool + 14 * TILEB, u);
}

// ---- K3: L3 + L2 + L1 + L0 + head; 1 block x 512 thr ----
__global__ __launch_bounds__(512) void k_top2(
    const int* __restrict__ wid, const float* __restrict__ emb,
    const float* __restrict__ Ww, const float* __restrict__ Wb,
    const float* __restrict__ gamma, const float* __restrict__ beta,
    const float* __restrict__ Pw, const float* __restrict__ Pb,
    const int* __restrict__ label, const short* __restrict__ hin,
    float* __restrict__ out) {
  __shared__ __align__(16) short pool[31 * TILEB];
  __shared__ float rootf[1024];
  __shared__ float lred[10];
  const int u = threadIdx.x;
  const int wv = u >> 6, l = u & 63;
  NodeParams P = load_params(Ww, Wb, gamma, beta, l);
  // wave w: stage its own children (2w normal, 2w+1 transp) + own L3 CW ->
  // L3 is fully same-wave, no barrier needed before it.
  stage_bf16(pool + 2 * wv * TILEB, hin + (size_t)(2 * wv) * 1024, l, false);
  stage_bf16(pool + (2 * wv + 1) * TILEB, hin + (size_t)(2 * wv + 1) * 1024, l,
             true);
  cw_prep(pool + (16 + wv) * TILEB, emb + (size_t)wid[7 + wv] * 1024, P, l);
  // L3: 8 nodes, one per wave (same-wave children + CW)
  node3(pool + 2 * wv * TILEB, pool + (2 * wv + 1) * TILEB,
        pool + (16 + wv) * TILEB, P, l, pool + (16 + wv) * TILEB,
        (wv & 1) != 0, nullptr);
  // extra CW preps (consumed post-barrier): L2 -> 24..27, L1 -> 28,29, L0 -> 30
  if (wv < 4)
    cw_prep(pool + (24 + wv) * TILEB, emb + (size_t)wid[3 + wv] * 1024, P, l);
  else if (wv < 6)
    cw_prep(pool + (28 + (wv - 4)) * TILEB,
            emb + (size_t)wid[1 + (wv - 4)] * 1024, P, l);
  else if (wv == 6)
    cw_prep(pool + 30 * TILEB, emb + (size_t)wid[0] * 1024, P, l);
  __syncthreads();
  // L2: 4 nodes on waves 0..3
  if (wv < 4)
    node3(pool + (16 + 2 * wv) * TILEB, pool + (17 + 2 * wv) * TILEB,
          pool + (24 + wv) * TILEB, P, l, pool + (24 + wv) * TILEB,
          (wv & 1) != 0, nullptr);
  __syncthreads();
  // L1: 2 nodes on waves 0,1
  if (wv < 2)
    node3(pool + (24 + 2 * wv) * TILEB, pool + (25 + 2 * wv) * TILEB,
          pool + (28 + wv) * TILEB, P, l, pool + (28 + wv) * TILEB,
          (wv & 1) != 0, nullptr);
  __syncthreads();
  // L0 -> fp32 root
  if (wv == 0)
    node3(pool + 28 * TILEB, pool + 29 * TILEB, pool + 30 * TILEB, P, l,
          nullptr, false, rootf);
  __syncthreads();
  // head: wave wv handles classes wv and wv+8
  #pragma unroll
  for (int q = 0; q < 2; ++q) {
    const int c = wv + 8 * q;
    if (c < 10) {
      float p = 0.f;
      #pragma unroll
      for (int t = 0; t < 4; ++t) {
        float4 r4 = *(const float4*)&rootf[l * 16 + t * 4];
        float4 w4 = *(const float4*)&Pw[c * 1024 + l * 16 + t * 4];
        p += r4.x * w4.x + r4.y * w4.y + r4.z * w4.z + r4.w * w4.w;
      }
      #pragma unroll
      for (int off = 32; off; off >>= 1) p += __shfl_xor(p, off);
      if (l == 0) lred[c] = p + Pb[c];
    }
  }
  __syncthreads();
  if (u == 0) {
    float mmax = lred[0];
    int am = 0;
    #pragma unroll
    for (int c = 1; c < 10; ++c)
      if (lred[c] > mmax) { mmax = lred[c]; am = c; }
    float sum = 0.f;
    #pragma unroll
    for (int c = 0; c < 10; ++c) sum += expf(lred[c] - mmax);
    const float loss = -(lred[label[0]] - mmax - logf(sum));
    out[0] = (float)am;
    out[1] = loss;
  }
}

extern "C" void kernel_launch(void* const* d_in, const int* in_sizes, int n_in,
                              void* d_out, int out_size, void* d_ws, size_t ws_size,
                              hipStream_t stream) {
  const int* wid = (const int*)d_in[0];
  const int* label = (const int*)d_in[1];
  const float* emb = (const float*)d_in[2];
  const float* Ww = (const float*)d_in[3];
  const float* Wb = (const float*)d_in[4];
  const float* g = (const float*)d_in[5];
  const float* b = (const float*)d_in[6];
  const float* Pw = (const float*)d_in[7];
  const float* Pb = (const float*)d_in[8];
  float* out = (float*)d_out;

  short* h7 = (short*)d_ws;          // 128 tiles x 1024 bf16
  short* h4 = h7 + 128 * 1024;       // 16 tiles

  k_bot7<<<128, 512, 0, stream>>>(wid, emb, Ww, Wb, g, b, h7);
  k_mid16<<<16, 512, 0, stream>>>(wid, emb, Ww, Wb, g, b, h7, h4);
  k_top2<<<1, 512, 0, stream>>>(wid, emb, Ww, Wb, g, b, Pw, Pb, label, h4, out);
}